// Round 20
// baseline (47.010 us; speedup 1.0000x reference)
//
#include <hip/hip_runtime.h>
#include <hip/hip_fp16.h>

#define LN2D 0.6931471805599453094172321

typedef float v2f __attribute__((ext_vector_type(2)));

// lane l gets lane l-1's v; lane 0 gets fill. VALU DPP, no LDS.
__device__ __forceinline__ float shr1(float v, float fill) {
    return __int_as_float(__builtin_amdgcn_update_dpp(
        __float_as_int(fill), __float_as_int(v), 0x138 /*wave_shr:1*/, 0xF, 0xF, false));
}
// lane l gets lane l+1's v; lane 63 gets fill.
__device__ __forceinline__ float shl1(float v, float fill) {
    return __int_as_float(__builtin_amdgcn_update_dpp(
        __float_as_int(fill), __float_as_int(v), 0x130 /*wave_shl:1*/, 0xF, 0xF, false));
}

// DPP wave64 reduce (row_shr 1,2,4,8; bcast15; bcast31) -> valid in lane 63.
__device__ __forceinline__ float wave_sum63(float x) {
    int t;
    t = __builtin_amdgcn_update_dpp(0, __float_as_int(x), 0x111, 0xF, 0xF, true);
    x += __int_as_float(t);
    t = __builtin_amdgcn_update_dpp(0, __float_as_int(x), 0x112, 0xF, 0xF, true);
    x += __int_as_float(t);
    t = __builtin_amdgcn_update_dpp(0, __float_as_int(x), 0x114, 0xF, 0xF, true);
    x += __int_as_float(t);
    t = __builtin_amdgcn_update_dpp(0, __float_as_int(x), 0x118, 0xF, 0xF, true);
    x += __int_as_float(t);
    t = __builtin_amdgcn_update_dpp(0, __float_as_int(x), 0x142, 0xA, 0xF, true);
    x += __int_as_float(t);
    t = __builtin_amdgcn_update_dpp(0, __float_as_int(x), 0x143, 0xC, 0xF, true);
    x += __int_as_float(t);
    return x;
}

__device__ __forceinline__ float wave_max63(float x) {
    int iv = __float_as_int(x); int t;
    t = __builtin_amdgcn_update_dpp(iv, iv, 0x111, 0xF, 0xF, false);
    x = fmaxf(x, __int_as_float(t)); iv = __float_as_int(x);
    t = __builtin_amdgcn_update_dpp(iv, iv, 0x112, 0xF, 0xF, false);
    x = fmaxf(x, __int_as_float(t)); iv = __float_as_int(x);
    t = __builtin_amdgcn_update_dpp(iv, iv, 0x114, 0xF, 0xF, false);
    x = fmaxf(x, __int_as_float(t)); iv = __float_as_int(x);
    t = __builtin_amdgcn_update_dpp(iv, iv, 0x118, 0xF, 0xF, false);
    x = fmaxf(x, __int_as_float(t)); iv = __float_as_int(x);
    t = __builtin_amdgcn_update_dpp(iv, iv, 0x142, 0xA, 0xF, false);
    x = fmaxf(x, __int_as_float(t)); iv = __float_as_int(x);
    t = __builtin_amdgcn_update_dpp(iv, iv, 0x143, 0xC, 0xF, false);
    x = fmaxf(x, __int_as_float(t));
    return x;
}

__device__ __forceinline__ float rdl63(float v) {
    return __int_as_float(__builtin_amdgcn_readlane(__float_as_int(v), 63));
}

// fp8-e5m2 = high byte of f16. Encode with +0x80 round.
__device__ __forceinline__ unsigned short pk_fp8(float a, float b) {
    const unsigned short ha = __builtin_bit_cast(unsigned short, __float2half_rn(a));
    const unsigned short hb = __builtin_bit_cast(unsigned short, __float2half_rn(b));
    const unsigned ua = ((unsigned)ha + 0x80u) >> 8;
    const unsigned ub = (((unsigned)hb + 0x80u) >> 8) << 8;
    return (unsigned short)(ua | ub);
}
// decode both fp8 in 3 ops: byte_perm builds [e3|0|e1|0] = half2, then 2 cvts
__device__ __forceinline__ float2 dec2(unsigned short u) {
    const unsigned pk = __byte_perm((unsigned)u, 0u, 0x01040004);
    return __half22float2(__builtin_bit_cast(__half2, pk));
}

// One block per batch, 512 threads (8 waves), 64 KB LDS (fp8 pairs, all 512
// rows). Produce: each wave 64 rows, lean (no per-row reduce spine); lse via
// transposed re-read (1 row/lane, 1 log/lane). Chain: wave 0 runs fwd AND bwd
// 256-step chains interleaved (issue-floor-bound, not latency-bound), decode
// trimmed to 3 ops, and combines P = sum_s alpha*beta in-register (double).
__global__ __launch_bounds__(512) void ctc_fused(const int* __restrict__ yt,
                                                 const float* __restrict__ yp,
                                                 float* __restrict__ part,
                                                 float* __restrict__ accW) {
    constexpr int L = 128;
    const int b    = blockIdx.x;
    const int w    = threadIdx.x >> 6;     // 0..7
    const int lane = threadIdx.x & 63;

    __shared__ unsigned short g[512][64];  // 64 KB: fp8(e1) | fp8(e3)<<8

    const int2 cc = *reinterpret_cast<const int2*>(yt + b * L + 2 * lane);
    const int c1 = cc.x, c3 = cc.y;
    const int sl1 = c1 >> 1, sh1v = (c1 & 1) << 4;
    const int sl3 = c3 >> 1, sh3v = (c3 & 1) << 4;

    // ---------------- produce: 64 rows per wave (lean) ----------------
    float xbsum = 0.0f;   // sum of x_blank over this wave's rows (lane-uniform)
    const float* src = yp + ((size_t)b * 512 + w * 64) * 128 + lane * 2;
    v2f A8[8], B8[8];

#define ISSUE8(d_, p_)                                                         \
    asm volatile(                                                              \
        "global_load_dwordx2 %0, %8, off\n\t"                                  \
        "global_load_dwordx2 %1, %8, off offset:512\n\t"                       \
        "global_load_dwordx2 %2, %8, off offset:1024\n\t"                      \
        "global_load_dwordx2 %3, %8, off offset:1536\n\t"                      \
        "global_load_dwordx2 %4, %8, off offset:2048\n\t"                      \
        "global_load_dwordx2 %5, %8, off offset:2560\n\t"                      \
        "global_load_dwordx2 %6, %8, off offset:3072\n\t"                      \
        "global_load_dwordx2 %7, %8, off offset:3584"                          \
        : "=&v"(d_[0]), "=&v"(d_[1]), "=&v"(d_[2]), "=&v"(d_[3]),              \
          "=&v"(d_[4]), "=&v"(d_[5]), "=&v"(d_[6]), "=&v"(d_[7])               \
        : "v"(p_)                                                              \
        : "memory");

#define WAITN(n_)                                                              \
    {                                                                          \
        asm volatile("s_waitcnt vmcnt(" #n_ ")" ::: "memory");                 \
        __builtin_amdgcn_sched_barrier(0);                                     \
    }

#define PROC8(buf_, rb_)                                                       \
    {                                                                          \
        _Pragma("unroll")                                                      \
        for (int i = 0; i < 8; ++i) {                                          \
            const float vx = buf_[i].x, vy = buf_[i].y;                        \
            const float xbv = rdl63(vy);      /* blank = lane63.y */           \
            xbsum += xbv;                                                      \
            const __half2 hh = __floats2half2_rn(vx, vy);                      \
            const int hb = __builtin_bit_cast(int, hh);                        \
            const int q1 = __shfl(hb, sl1, 64);                                \
            const int q3 = __shfl(hb, sl3, 64);                                \
            const float x1 = __half2float(__builtin_bit_cast(__half, (unsigned short)(q1 >> sh1v))); \
            const float x3 = __half2float(__builtin_bit_cast(__half, (unsigned short)(q3 >> sh3v))); \
            g[w * 64 + (rb_) + i][lane] = pk_fp8(__expf(x1 - xbv), __expf(x3 - xbv)); \
        }                                                                      \
    }

    ISSUE8(A8, src)
    ISSUE8(B8, src + 8 * 128)
    WAITN(8)  PROC8(A8, 0)   ISSUE8(A8, src + 16 * 128)
    WAITN(8)  PROC8(B8, 8)   ISSUE8(B8, src + 24 * 128)
    WAITN(8)  PROC8(A8, 16)  ISSUE8(A8, src + 32 * 128)
    WAITN(8)  PROC8(B8, 24)  ISSUE8(B8, src + 40 * 128)
    WAITN(8)  PROC8(A8, 32)  ISSUE8(A8, src + 48 * 128)
    WAITN(8)  PROC8(B8, 40)  ISSUE8(B8, src + 56 * 128)
    WAITN(8)  PROC8(A8, 48)
    WAITN(0)  PROC8(B8, 56)

    // transposed lse: lane owns row w*64+lane (L3-resident re-read)
    {
        const float* pb = yp + ((size_t)b * 512 + w * 64 + lane) * 128;
        float s = 0.0f;
        #pragma unroll
        for (int j = 0; j < 32; ++j) {
            const float4 f = *reinterpret_cast<const float4*>(pb + 4 * j);
            s += (__expf(f.x) + __expf(f.y)) + (__expf(f.z) + __expf(f.w));
        }
        const float lg = __logf(s);
        const float tot = rdl63(wave_sum63(lg));
        if (lane == 0) accW[b * 8 + w] = tot - xbsum;
    }
    __syncthreads();

    // ---------------- dual chain: wave 0 only ----------------
    if (w == 0) {
        const int cprev = __shfl_up(c3, 1, 64);
        const float sk1 = (lane > 0 && c1 != cprev) ? 1.0f : 0.0f;
        const float sk3 = (c3 != c1) ? 1.0f : 0.0f;
        const float skB3 = shl1(sk1, 0.0f);
        const int llen = __popcll(__ballot(c1 != 0)) + __popcll(__ballot(c3 != 0));

        float o0, o1, o2, o3, o4;   // forward alpha
        float q0, q1, q2, q3, q4;   // backward beta
        int   EF = 0, EB = 0;
        unsigned short fr[8], br[8];

#define RENORM5(a0_, a1_, a2_, a3_, a4_, Ec_)                                  \
    {                                                                          \
        float mr = fmaxf(fmaxf(fmaxf(a0_, a1_), fmaxf(a2_, a3_)), a4_);        \
        const float mru = rdl63(wave_max63(mr));                               \
        const int ie = (__float_as_int(mru) >> 23) & 0xFF;                     \
        const float sc = __int_as_float((253 - ie) << 23);                     \
        a0_ *= sc; a1_ *= sc; a2_ *= sc; a3_ *= sc; a4_ *= sc;                 \
        Ec_ += ie - 126;                                                       \
    }

#define FSTEP(bits_, rn_)                                                      \
    {                                                                          \
        const float2 ee = dec2(bits_);                                         \
        const float pm = shr1(o3, 0.0f);                                       \
        const float n0 = o0 + pm;                                              \
        const float n1 = (o1 + o0 + sk1 * pm) * ee.x;                          \
        const float n2 = o2 + o1;                                              \
        const float n3 = (o3 + o2 + sk3 * o1) * ee.y;                          \
        o4 += o3;                                                              \
        o0 = n0; o1 = n1; o2 = n2; o3 = n3;                                    \
        if (rn_) RENORM5(o0, o1, o2, o3, o4, EF);                              \
    }

#define BSTEP(bits_, rn_)                                                      \
    {                                                                          \
        const float2 ee = dec2(bits_);                                         \
        const float g1 = q1 * ee.x;                                            \
        const float g3 = q3 * ee.y;                                            \
        const float pm0 = shl1(q0, q4);      /* beta(4l+4); lane63 -> q4 */    \
        const float pm1 = shl1(g1, 0.0f);    /* gamma(4l+5); lane63 -> 0 */    \
        const float n0 = q0 + g1;                                              \
        const float n1 = g1 + q2 + sk3 * g3;                                   \
        const float n2 = q2 + g3;                                              \
        const float n3 = g3 + pm0 + skB3 * pm1;                                \
        q0 = n0; q1 = n1; q2 = n2; q3 = n3;                                    \
        if (rn_) RENORM5(q0, q1, q2, q3, q4, EB);                              \
    }

        #pragma unroll
        for (int i = 0; i < 8; ++i) { fr[i] = g[i][lane]; br[i] = g[511 - i][lane]; }

        {   // fwd init (consumes row 0)
            const float2 e0 = dec2(fr[0]);
            o0 = (lane == 0) ? 1.0f : 0.0f;
            o1 = (lane == 0) ? e0.x : 0.0f;
            o2 = 0.0f; o3 = 0.0f; o4 = 0.0f;
        }
        {   // bwd init at readout states s = 2*llen, 2*llen-1
            const int sA = 2 * llen, sB = 2 * llen - 1;
            q0 = (4 * lane + 0 == sA) ? 1.0f : 0.0f;
            q1 = (4 * lane + 1 == sB) ? 1.0f : 0.0f;
            q2 = (4 * lane + 2 == sA) ? 1.0f : 0.0f;
            q3 = (4 * lane + 3 == sB) ? 1.0f : 0.0f;
            q4 = (llen == 128 && lane == 63) ? 1.0f : 0.0f;   // s = 256
        }

        // k = 0: bwd row 511; refill slot 0
        BSTEP(br[0], false);
        fr[0] = g[8][lane]; br[0] = g[503][lane];
        // k = 1..7
        #pragma unroll
        for (int k = 1; k < 8; ++k) {
            FSTEP(fr[k], false);
            BSTEP(br[k], false);
            fr[k] = g[k + 8][lane]; br[k] = g[511 - k - 8][lane];
        }
        // k = 8..247: interleaved fwd row k / bwd row 511-k, refill +8 ahead
        for (int kb = 8; kb < 248; kb += 8) {
            #pragma unroll
            for (int j = 0; j < 8; ++j) {
                const int k = kb + j;
                FSTEP(fr[j], (k & 31) == 0);
                BSTEP(br[j], (k & 31) == 31);
                fr[j] = g[k + 8][lane]; br[j] = g[511 - k - 8][lane];
            }
        }
        // k = 248..255: drain
        #pragma unroll
        for (int k = 248; k < 256; ++k) {
            FSTEP(fr[k & 7], false);
            BSTEP(br[k & 7], (k & 31) == 31);
        }

        // in-register combine at t = 255 (double: fp32 products of two
        // max-normalized fields underflow when argmax states misalign)
        double p = (double)o0 * (double)q0 + (double)o1 * (double)q1
                 + (double)o2 * (double)q2 + (double)o3 * (double)q3;
        if (lane == 63) p += (double)o4 * (double)q4;
        #pragma unroll
        for (int off = 32; off > 0; off >>= 1) p += __shfl_xor(p, off, 64);
        if (lane == 0)
            part[b] = (float)(log(p) + (double)(EF + EB) * LN2D);
#undef BSTEP
#undef FSTEP
#undef RENORM5
    }
#undef PROC8
#undef WAITN
#undef ISSUE8
}

// finalize: loss[b] = -(part[b] - sum_w accW[b*8+w]); mean over B=256.
__global__ __launch_bounds__(256) void finalize(const float* __restrict__ part,
                                                const float* __restrict__ accW,
                                                float* __restrict__ out) {
    __shared__ float red[256];
    const int tid = threadIdx.x;
    float ls = 0.0f;
    #pragma unroll
    for (int j = 0; j < 8; ++j) ls += accW[tid * 8 + j];
    red[tid] = -(part[tid] - ls);
    __syncthreads();
    for (int off = 128; off > 0; off >>= 1) {
        if (tid < off) red[tid] += red[tid + off];
        __syncthreads();
    }
    if (tid == 0) out[0] = red[0] * (1.0f / 256.0f);
}

extern "C" void kernel_launch(void* const* d_in, const int* in_sizes, int n_in,
                              void* d_out, int out_size, void* d_ws, size_t ws_size,
                              hipStream_t stream) {
    constexpr int B = 256;
    const int*   y_true = (const int*)d_in[0];
    const float* y_pred = (const float*)d_in[1];
    float* out = (float*)d_out;

    float* part = (float*)d_ws;            // B floats
    float* accW = part + B;                // B*8 floats

    ctc_fused<<<B, 512, 0, stream>>>(y_true, y_pred, part, accW);
    finalize<<<1, 256, 0, stream>>>(part, accW, out);
}

// Round 22
// 46.502 us; speedup vs baseline: 1.0109x; 1.0109x over previous
//
#include <hip/hip_runtime.h>
#include <hip/hip_fp16.h>

#define LN2D 0.6931471805599453094172321

// lane l gets lane l-1's v; lane 0 gets fill. VALU DPP, no LDS.
__device__ __forceinline__ float shr1(float v, float fill) {
    return __int_as_float(__builtin_amdgcn_update_dpp(
        __float_as_int(fill), __float_as_int(v), 0x138 /*wave_shr:1*/, 0xF, 0xF, false));
}
// lane l gets lane l+1's v; lane 63 gets fill.
__device__ __forceinline__ float shl1(float v, float fill) {
    return __int_as_float(__builtin_amdgcn_update_dpp(
        __float_as_int(fill), __float_as_int(v), 0x130 /*wave_shl:1*/, 0xF, 0xF, false));
}

// DPP wave64 reduce (row_shr 1,2,4,8; bcast15; bcast31) -> valid in lane 63.
__device__ __forceinline__ float wave_sum63(float x) {
    int t;
    t = __builtin_amdgcn_update_dpp(0, __float_as_int(x), 0x111, 0xF, 0xF, true);
    x += __int_as_float(t);
    t = __builtin_amdgcn_update_dpp(0, __float_as_int(x), 0x112, 0xF, 0xF, true);
    x += __int_as_float(t);
    t = __builtin_amdgcn_update_dpp(0, __float_as_int(x), 0x114, 0xF, 0xF, true);
    x += __int_as_float(t);
    t = __builtin_amdgcn_update_dpp(0, __float_as_int(x), 0x118, 0xF, 0xF, true);
    x += __int_as_float(t);
    t = __builtin_amdgcn_update_dpp(0, __float_as_int(x), 0x142, 0xA, 0xF, true);
    x += __int_as_float(t);
    t = __builtin_amdgcn_update_dpp(0, __float_as_int(x), 0x143, 0xC, 0xF, true);
    x += __int_as_float(t);
    return x;
}

__device__ __forceinline__ float wave_max63(float x) {
    int iv = __float_as_int(x); int t;
    t = __builtin_amdgcn_update_dpp(iv, iv, 0x111, 0xF, 0xF, false);
    x = fmaxf(x, __int_as_float(t)); iv = __float_as_int(x);
    t = __builtin_amdgcn_update_dpp(iv, iv, 0x112, 0xF, 0xF, false);
    x = fmaxf(x, __int_as_float(t)); iv = __float_as_int(x);
    t = __builtin_amdgcn_update_dpp(iv, iv, 0x114, 0xF, 0xF, false);
    x = fmaxf(x, __int_as_float(t)); iv = __float_as_int(x);
    t = __builtin_amdgcn_update_dpp(iv, iv, 0x118, 0xF, 0xF, false);
    x = fmaxf(x, __int_as_float(t)); iv = __float_as_int(x);
    t = __builtin_amdgcn_update_dpp(iv, iv, 0x142, 0xA, 0xF, false);
    x = fmaxf(x, __int_as_float(t)); iv = __float_as_int(x);
    t = __builtin_amdgcn_update_dpp(iv, iv, 0x143, 0xC, 0xF, false);
    x = fmaxf(x, __int_as_float(t));
    return x;
}

__device__ __forceinline__ float rdl63(float v) {
    return __int_as_float(__builtin_amdgcn_readlane(__float_as_int(v), 63));
}

// pack two f32 as bf16 pair (round-to-nearest-even): lo = a, hi = b
__device__ __forceinline__ int pk_bf16(float a, float b) {
    unsigned ua = __float_as_uint(a), ub = __float_as_uint(b);
    ua = (ua + 0x7FFFu + ((ua >> 16) & 1u)) >> 16;
    ub = (ub + 0x7FFFu + ((ub >> 16) & 1u)) & 0xFFFF0000u;
    return (int)(ua | ub);
}

// Kernel 1 (prep): one wave per (b,t) row, full-occupancy TLP (R14-proven
// structure; G payload = pre-exponentiated bf16 pair, R16-proven math).
__global__ __launch_bounds__(256) void prep(const int* __restrict__ yt,
                                            const float* __restrict__ yp,
                                            float* __restrict__ lsb,
                                            int* __restrict__ G) {
    const int row  = blockIdx.x * 4 + (threadIdx.x >> 6);
    const int lane = threadIdx.x & 63;
    const int b    = row >> 9;                      // T = 512
    const float2 v = *reinterpret_cast<const float2*>(yp + (size_t)row * 128 + lane * 2);

    const float sall = rdl63(wave_sum63(__expf(v.x) + __expf(v.y)));
    const float xbv  = rdl63(v.y);                  // class 127 (blank) = lane63.y

    const int2 cc = *reinterpret_cast<const int2*>(yt + b * 128 + 2 * lane);
    const int c1 = cc.x, c3 = cc.y;

    const __half2 hh = __floats2half2_rn(v.x, v.y);
    const int hbits = __builtin_bit_cast(int, hh);
    const int g1 = __shfl(hbits, c1 >> 1, 64);
    const int g3 = __shfl(hbits, c3 >> 1, 64);
    const float x1 = __half2float(__builtin_bit_cast(__half, (unsigned short)(g1 >> ((c1 & 1) << 4))));
    const float x3 = __half2float(__builtin_bit_cast(__half, (unsigned short)(g3 >> ((c3 & 1) << 4))));

    G[(size_t)row * 64 + lane] = pk_bf16(__expf(x1 - xbv), __expf(x3 - xbv));
    if (lane == 0) lsb[row] = __logf(sall) - xbv;
}

// Kernel 2: ONE WAVE per batch runs fwd (rows 0..255) AND bwd (rows 511..256)
// chains INTERLEAVED (two independent dep-chains -> ILP). PF=16 global rings
// per direction. Renorm rows identical to R14 (fwd 32..224, bwd 480..256).
// Combine P = sum_s alpha(s)*beta(s) in-register in DOUBLE (fp32 underflows
// when the two fields' argmax states misalign).
__global__ __launch_bounds__(64) void ctc_dual(const int* __restrict__ yt,
                                               const int* __restrict__ G,
                                               const float* __restrict__ lsb,
                                               float* __restrict__ loss) {
    constexpr int L = 128;
    constexpr int PF = 16;
    const int b    = blockIdx.x;
    const int lane = threadIdx.x;

    const int2 cc = *reinterpret_cast<const int2*>(yt + b * L + 2 * lane);
    const int c1 = cc.x, c3 = cc.y;
    const int cprev = __shfl_up(c3, 1, 64);
    const float sk1 = (lane > 0 && c1 != cprev) ? 1.0f : 0.0f;
    const float sk3 = (c3 != c1) ? 1.0f : 0.0f;
    const float skB3 = shl1(sk1, 0.0f);
    const int llen = __popcll(__ballot(c1 != 0)) + __popcll(__ballot(c3 != 0));

    const int* gi = G + (size_t)b * 512 * 64 + lane;

    float o0, o1, o2, o3, o4;   // forward alpha
    float q0, q1, q2, q3, q4;   // backward beta
    int   EF = 0, EB = 0;
    int   fr[PF], br[PF];

#define RENORM5(a0_, a1_, a2_, a3_, a4_, Ec_)                                  \
    {                                                                          \
        float mr = fmaxf(fmaxf(fmaxf(a0_, a1_), fmaxf(a2_, a3_)), a4_);        \
        const float mru = rdl63(wave_max63(mr));                               \
        const int ie = (__float_as_int(mru) >> 23) & 0xFF;                     \
        const float sc = __int_as_float((253 - ie) << 23);                     \
        a0_ *= sc; a1_ *= sc; a2_ *= sc; a3_ *= sc; a4_ *= sc;                 \
        Ec_ += ie - 126;                                                       \
    }

#define FSTEP(bits_, rn_)                                                      \
    {                                                                          \
        const float e1 = __int_as_float((bits_) << 16);                        \
        const float e3 = __int_as_float((bits_) & 0xFFFF0000);                 \
        const float pm = shr1(o3, 0.0f);                                       \
        const float n0 = o0 + pm;                                              \
        const float n1 = (o1 + o0 + sk1 * pm) * e1;                            \
        const float n2 = o2 + o1;                                              \
        const float n3 = (o3 + o2 + sk3 * o1) * e3;                            \
        o4 += o3;                                                              \
        o0 = n0; o1 = n1; o2 = n2; o3 = n3;                                    \
        if (rn_) RENORM5(o0, o1, o2, o3, o4, EF);                              \
    }

#define BSTEP(bits_, rn_)                                                      \
    {                                                                          \
        const float e1 = __int_as_float((bits_) << 16);                        \
        const float e3 = __int_as_float((bits_) & 0xFFFF0000);                 \
        const float g1 = q1 * e1;                                              \
        const float g3 = q3 * e3;                                              \
        const float pm0 = shl1(q0, q4);      /* beta(4l+4); lane63 -> q4 */    \
        const float pm1 = shl1(g1, 0.0f);    /* gamma(4l+5); lane63 -> 0 */    \
        const float n0 = q0 + g1;                                              \
        const float n1 = g1 + q2 + sk3 * g3;                                   \
        const float n2 = q2 + g3;                                              \
        const float n3 = g3 + pm0 + skB3 * pm1;                                \
        q0 = n0; q1 = n1; q2 = n2; q3 = n3;                                    \
        if (rn_) RENORM5(q0, q1, q2, q3, q4, EB);                              \
    }

    // prologue loads: fwd rows 0..15, bwd rows 511..496
    #pragma unroll
    for (int i = 0; i < PF; ++i) { fr[i] = gi[i * 64]; br[i] = gi[(511 - i) * 64]; }

    {   // fwd init consumes row 0
        const float e10 = __int_as_float(fr[0] << 16);
        o0 = (lane == 0) ? 1.0f : 0.0f;
        o1 = (lane == 0) ? e10 : 0.0f;
        o2 = 0.0f; o3 = 0.0f; o4 = 0.0f;
    }
    {   // bwd init at readout states s = 2*llen, 2*llen-1
        const int sA = 2 * llen, sB = 2 * llen - 1;
        q0 = (4 * lane + 0 == sA) ? 1.0f : 0.0f;
        q1 = (4 * lane + 1 == sB) ? 1.0f : 0.0f;
        q2 = (4 * lane + 2 == sA) ? 1.0f : 0.0f;
        q3 = (4 * lane + 3 == sB) ? 1.0f : 0.0f;
        q4 = (llen == 128 && lane == 63) ? 1.0f : 0.0f;   // s = 256
    }

    // k = 0: bwd row 511; refill slot 0 (fwd row 16, bwd row 495)
    BSTEP(br[0], false);
    fr[0] = gi[PF * 64]; br[0] = gi[(511 - PF) * 64];
    // k = 1..15: fwd rows 1..15, bwd rows 510..496; refill +PF ahead
    #pragma unroll
    for (int k = 1; k < PF; ++k) {
        FSTEP(fr[k], false);
        BSTEP(br[k], false);
        fr[k] = gi[(k + PF) * 64];
        br[k] = gi[(511 - k - PF) * 64];
    }
    // k = 16..239: fwd rows k (renorm 32..224), bwd rows 511-k (renorm 480..288)
    for (int kb = PF; kb < 240; kb += PF) {
        #pragma unroll
        for (int j = 0; j < PF; ++j) {
            const int k = kb + j;
            FSTEP(fr[j], (k & 31) == 0);
            BSTEP(br[j], (k & 31) == 31);
            fr[j] = gi[(k + PF) * 64];
            br[j] = gi[(511 - k - PF) * 64];
        }
    }
    // k = 240..255: fwd rows 240..255; bwd rows 271..256 (renorm row 256 at k=255)
    #pragma unroll
    for (int k = 240; k < 256; ++k) {
        FSTEP(fr[k & (PF - 1)], false);
        BSTEP(br[k & (PF - 1)], (k & 31) == 31);
    }

    // per-batch lse sum (lse - x_blank over 512 rows)
    const float* lrow = lsb + (size_t)b * 512 + lane * 8;
    const float4 la = *reinterpret_cast<const float4*>(lrow);
    const float4 lc = *reinterpret_cast<const float4*>(lrow + 4);
    float lsv = ((la.x + la.y) + (la.z + la.w)) + ((lc.x + lc.y) + (lc.z + lc.w));
    const float ls = rdl63(wave_sum63(lsv));

    // in-register combine at t = 255 (double precision)
    double p = (double)o0 * (double)q0 + (double)o1 * (double)q1
             + (double)o2 * (double)q2 + (double)o3 * (double)q3;
    if (lane == 63) p += (double)o4 * (double)q4;
    #pragma unroll
    for (int off = 32; off > 0; off >>= 1) p += __shfl_xor(p, off, 64);
    if (lane == 0) {
        const double lg = log(p) + (double)(EF + EB) * LN2D - (double)ls;
        loss[b] = -(float)lg;
    }
#undef BSTEP
#undef FSTEP
#undef RENORM5
}

// Kernel 3: deterministic mean over B=256 losses
__global__ __launch_bounds__(256) void finalize(const float* __restrict__ loss,
                                                float* __restrict__ out) {
    __shared__ float red[256];
    const int tid = threadIdx.x;
    red[tid] = loss[tid];
    __syncthreads();
    for (int off = 128; off > 0; off >>= 1) {
        if (tid < off) red[tid] += red[tid + off];
        __syncthreads();
    }
    if (tid == 0) out[0] = red[0] * (1.0f / 256.0f);
}

extern "C" void kernel_launch(void* const* d_in, const int* in_sizes, int n_in,
                              void* d_out, int out_size, void* d_ws, size_t ws_size,
                              hipStream_t stream) {
    constexpr int B = 256, T = 512;
    const int*   y_true = (const int*)d_in[0];
    const float* y_pred = (const float*)d_in[1];
    float* out = (float*)d_out;

    float* lsb  = (float*)d_ws;                      // B*T floats
    float* loss = lsb + (size_t)B * T;               // B floats
    int*   G    = (int*)(loss + B);                  // B*T*64 ints (33.5 MB)

    prep<<<(B * T) / 4, 256, 0, stream>>>(y_true, y_pred, lsb, G);
    ctc_dual<<<B, 64, 0, stream>>>(y_true, G, lsb, loss);
    finalize<<<1, 256, 0, stream>>>(loss, out);
}

// Round 23
// 40.893 us; speedup vs baseline: 1.1496x; 1.1372x over previous
//
#include <hip/hip_runtime.h>
#include <hip/hip_fp16.h>

#define LN2D 0.6931471805599453094172321

typedef float v2f __attribute__((ext_vector_type(2)));

// lane l gets lane l-1's v; lane 0 gets fill. VALU DPP, no LDS.
__device__ __forceinline__ float shr1(float v, float fill) {
    return __int_as_float(__builtin_amdgcn_update_dpp(
        __float_as_int(fill), __float_as_int(v), 0x138 /*wave_shr:1*/, 0xF, 0xF, false));
}
// lane l gets lane l+1's v; lane 63 gets fill.
__device__ __forceinline__ float shl1(float v, float fill) {
    return __int_as_float(__builtin_amdgcn_update_dpp(
        __float_as_int(fill), __float_as_int(v), 0x130 /*wave_shl:1*/, 0xF, 0xF, false));
}

// DPP wave64 reduce (row_shr 1,2,4,8; bcast15; bcast31) -> valid in lane 63.
__device__ __forceinline__ float wave_sum63(float x) {
    int t;
    t = __builtin_amdgcn_update_dpp(0, __float_as_int(x), 0x111, 0xF, 0xF, true);
    x += __int_as_float(t);
    t = __builtin_amdgcn_update_dpp(0, __float_as_int(x), 0x112, 0xF, 0xF, true);
    x += __int_as_float(t);
    t = __builtin_amdgcn_update_dpp(0, __float_as_int(x), 0x114, 0xF, 0xF, true);
    x += __int_as_float(t);
    t = __builtin_amdgcn_update_dpp(0, __float_as_int(x), 0x118, 0xF, 0xF, true);
    x += __int_as_float(t);
    t = __builtin_amdgcn_update_dpp(0, __float_as_int(x), 0x142, 0xA, 0xF, true);
    x += __int_as_float(t);
    t = __builtin_amdgcn_update_dpp(0, __float_as_int(x), 0x143, 0xC, 0xF, true);
    x += __int_as_float(t);
    return x;
}

__device__ __forceinline__ float wave_max63(float x) {
    int iv = __float_as_int(x); int t;
    t = __builtin_amdgcn_update_dpp(iv, iv, 0x111, 0xF, 0xF, false);
    x = fmaxf(x, __int_as_float(t)); iv = __float_as_int(x);
    t = __builtin_amdgcn_update_dpp(iv, iv, 0x112, 0xF, 0xF, false);
    x = fmaxf(x, __int_as_float(t)); iv = __float_as_int(x);
    t = __builtin_amdgcn_update_dpp(iv, iv, 0x114, 0xF, 0xF, false);
    x = fmaxf(x, __int_as_float(t)); iv = __float_as_int(x);
    t = __builtin_amdgcn_update_dpp(iv, iv, 0x118, 0xF, 0xF, false);
    x = fmaxf(x, __int_as_float(t)); iv = __float_as_int(x);
    t = __builtin_amdgcn_update_dpp(iv, iv, 0x142, 0xA, 0xF, false);
    x = fmaxf(x, __int_as_float(t)); iv = __float_as_int(x);
    t = __builtin_amdgcn_update_dpp(iv, iv, 0x143, 0xC, 0xF, false);
    x = fmaxf(x, __int_as_float(t));
    return x;
}

__device__ __forceinline__ float rdl63(float v) {
    return __int_as_float(__builtin_amdgcn_readlane(__float_as_int(v), 63));
}

// pack two f32 as bf16 pair (round-to-nearest-even): lo = a, hi = b
__device__ __forceinline__ int pk_bf16(float a, float b) {
    unsigned ua = __float_as_uint(a), ub = __float_as_uint(b);
    ua = (ua + 0x7FFFu + ((ua >> 16) & 1u)) >> 16;
    ub = (ub + 0x7FFFu + ((ub >> 16) & 1u)) & 0xFFFF0000u;
    return (int)(ua | ub);
}

#define VSTRIDE 260

// One block per (batch, half): 4 waves produce this half's 256 rows of
// PRE-EXPONENTIATED emissions e1=exp(x[c1]-xb), e3=exp(x[c3]-xb) (bf16 pair)
// into LDS; wave 0 then runs the 256-step half-chain reading LDS through an
// 8-deep static-index register ring (no transcendentals on the chain).
__global__ __launch_bounds__(256) void ctc_half(const int* __restrict__ yt,
                                                const float* __restrict__ yp,
                                                float* __restrict__ V,
                                                int* __restrict__ E,
                                                float* __restrict__ accW) {
    constexpr int L = 128;
    const int bh   = blockIdx.x;          // b*2 + h
    const int b    = bh >> 1, h = bh & 1;
    const int w    = threadIdx.x >> 6;
    const int lane = threadIdx.x & 63;

    __shared__ int g[256][64];            // 64 KB: bf16(e1)|bf16(e3)<<16

    const int2 cc = *reinterpret_cast<const int2*>(yt + b * L + 2 * lane);
    const int c1 = cc.x, c3 = cc.y;
    const int sl1 = c1 >> 1, sh1v = (c1 & 1) << 4;
    const int sl3 = c3 >> 1, sh3v = (c3 & 1) << 4;

    // ---------------- produce: 64 rows per wave ----------------
    float acc = 0.0f;
    const float* src = yp + ((size_t)b * 512 + h * 256 + w * 64) * 128 + lane * 2;
    v2f A8[8], B8[8];

#define ISSUE8(d_, p_)                                                         \
    asm volatile(                                                              \
        "global_load_dwordx2 %0, %8, off\n\t"                                  \
        "global_load_dwordx2 %1, %8, off offset:512\n\t"                       \
        "global_load_dwordx2 %2, %8, off offset:1024\n\t"                      \
        "global_load_dwordx2 %3, %8, off offset:1536\n\t"                      \
        "global_load_dwordx2 %4, %8, off offset:2048\n\t"                      \
        "global_load_dwordx2 %5, %8, off offset:2560\n\t"                      \
        "global_load_dwordx2 %6, %8, off offset:3072\n\t"                      \
        "global_load_dwordx2 %7, %8, off offset:3584"                          \
        : "=&v"(d_[0]), "=&v"(d_[1]), "=&v"(d_[2]), "=&v"(d_[3]),              \
          "=&v"(d_[4]), "=&v"(d_[5]), "=&v"(d_[6]), "=&v"(d_[7])               \
        : "v"(p_)                                                              \
        : "memory");

#define WAITN(n_)                                                              \
    {                                                                          \
        asm volatile("s_waitcnt vmcnt(" #n_ ")" ::: "memory");                 \
        __builtin_amdgcn_sched_barrier(0);                                     \
    }

#define PROC8(buf_, rb_)                                                       \
    {                                                                          \
        _Pragma("unroll")                                                      \
        for (int i = 0; i < 8; ++i) {                                          \
            const float vx = buf_[i].x, vy = buf_[i].y;                        \
            const float sall = rdl63(wave_sum63(__expf(vx) + __expf(vy)));     \
            const float xbv  = rdl63(vy);     /* blank = lane63.y */           \
            acc += __logf(sall) - xbv;                                         \
            const __half2 hh = __floats2half2_rn(vx, vy);                      \
            const int hb = __builtin_bit_cast(int, hh);                        \
            const int q1 = __shfl(hb, sl1, 64);                                \
            const int q3 = __shfl(hb, sl3, 64);                                \
            const float x1 = __half2float(__builtin_bit_cast(__half, (unsigned short)(q1 >> sh1v))); \
            const float x3 = __half2float(__builtin_bit_cast(__half, (unsigned short)(q3 >> sh3v))); \
            g[w * 64 + (rb_) + i][lane] =                                      \
                pk_bf16(__expf(x1 - xbv), __expf(x3 - xbv));                   \
        }                                                                      \
    }

    ISSUE8(A8, src)
    ISSUE8(B8, src + 8 * 128)
    WAITN(8)  PROC8(A8, 0)   ISSUE8(A8, src + 16 * 128)
    WAITN(8)  PROC8(B8, 8)   ISSUE8(B8, src + 24 * 128)
    WAITN(8)  PROC8(A8, 16)  ISSUE8(A8, src + 32 * 128)
    WAITN(8)  PROC8(B8, 24)  ISSUE8(B8, src + 40 * 128)
    WAITN(8)  PROC8(A8, 32)  ISSUE8(A8, src + 48 * 128)
    WAITN(8)  PROC8(B8, 40)  ISSUE8(B8, src + 56 * 128)
    WAITN(8)  PROC8(A8, 48)
    WAITN(0)  PROC8(B8, 56)

    if (lane == 0) accW[bh * 4 + w] = acc;
    __syncthreads();

    // ---------------- chain: wave 0 only ----------------
    if (w == 0) {
        const int cprev = __shfl_up(c3, 1, 64);
        const float sk1 = (lane > 0 && c1 != cprev) ? 1.0f : 0.0f;
        const float sk3 = (c3 != c1) ? 1.0f : 0.0f;
        const float skB3 = shl1(sk1, 0.0f);
        const int llen = __popcll(__ballot(c1 != 0)) + __popcll(__ballot(c3 != 0));

        float o0, o1, o2, o3, o4;
        int   Eacc = 0;
        int   er[8];

#define RENORM()                                                               \
    {                                                                          \
        float mr = fmaxf(fmaxf(fmaxf(o0, o1), fmaxf(o2, o3)), o4);             \
        const float mru = rdl63(wave_max63(mr));                               \
        const int ie = (__float_as_int(mru) >> 23) & 0xFF;                     \
        const float sc = __int_as_float((253 - ie) << 23);                     \
        o0 *= sc; o1 *= sc; o2 *= sc; o3 *= sc; o4 *= sc;                      \
        Eacc += ie - 126;                                                      \
    }

#define FSTEP(bits_, rn_)                                                      \
    {                                                                          \
        const float e1 = __int_as_float((bits_) << 16);                        \
        const float e3 = __int_as_float((bits_) & 0xFFFF0000);                 \
        const float pm = shr1(o3, 0.0f);                                       \
        const float n0 = o0 + pm;                                              \
        const float n1 = (o1 + o0 + sk1 * pm) * e1;                            \
        const float n2 = o2 + o1;                                              \
        const float n3 = (o3 + o2 + sk3 * o1) * e3;                            \
        o4 += o3;                                                              \
        o0 = n0; o1 = n1; o2 = n2; o3 = n3;                                    \
        if (rn_) RENORM();                                                     \
    }

#define BSTEP(bits_, rn_)                                                      \
    {                                                                          \
        const float e1 = __int_as_float((bits_) << 16);                        \
        const float e3 = __int_as_float((bits_) & 0xFFFF0000);                 \
        const float g1 = o1 * e1;                                              \
        const float g3 = o3 * e3;                                              \
        const float pm0 = shl1(o0, o4);      /* beta(4l+4); lane63 -> o4 */    \
        const float pm1 = shl1(g1, 0.0f);    /* gamma(4l+5); lane63 -> 0 */    \
        const float n0 = o0 + g1;                                              \
        const float n1 = g1 + o2 + sk3 * g3;                                   \
        const float n2 = o2 + g3;                                              \
        const float n3 = g3 + pm0 + skB3 * pm1;                                \
        o0 = n0; o1 = n1; o2 = n2; o3 = n3;                                    \
        if (rn_) RENORM();                                                     \
    }

        if (h == 0) {
            // forward: local rows 0..255 are global t = 0..255
            #pragma unroll
            for (int i = 0; i < 8; ++i) er[i] = g[i][lane];
            {
                const float e10 = __int_as_float(er[0] << 16);   // exp(d1) at t=0
                o0 = (lane == 0) ? 1.0f : 0.0f;
                o1 = (lane == 0) ? e10 : 0.0f;
                o2 = 0.0f; o3 = 0.0f; o4 = 0.0f;
            }
            er[0] = g[8][lane];
            #pragma unroll
            for (int t = 1; t < 8; ++t) { FSTEP(er[t], false); er[t] = g[t + 8][lane]; }
            #pragma unroll
            for (int tb = 8; tb < 248; tb += 8) {
                #pragma unroll
                for (int j = 0; j < 8; ++j) {
                    FSTEP(er[j], ((tb + j) & 31) == 0);
                    er[j] = g[tb + j + 8][lane];
                }
            }
            #pragma unroll
            for (int t = 248; t < 256; ++t) FSTEP(er[t & 7], false);
        } else {
            // backward: local rows 0..255 are global t = 256..511; walk down.
            #pragma unroll
            for (int i = 0; i < 8; ++i) er[i] = g[255 - i][lane];
            const int sA = 2 * llen, sB = 2 * llen - 1;   // readout states
            o0 = (4 * lane + 0 == sA) ? 1.0f : 0.0f;
            o1 = (4 * lane + 1 == sB) ? 1.0f : 0.0f;
            o2 = (4 * lane + 2 == sA) ? 1.0f : 0.0f;
            o3 = (4 * lane + 3 == sB) ? 1.0f : 0.0f;
            o4 = (llen == 128 && lane == 63) ? 1.0f : 0.0f;   // s = 256
            #pragma unroll
            for (int kb = 0; kb < 248; kb += 8) {
                #pragma unroll
                for (int j = 0; j < 8; ++j) {
                    const int r = 255 - (kb + j);
                    BSTEP(er[j], (r & 31) == 0);
                    er[j] = g[r - 8][lane];
                }
            }
            #pragma unroll
            for (int k = 248; k < 256; ++k) BSTEP(er[k & 7], ((255 - k) & 31) == 0);
        }

        // publish boundary vector (t = 255) + exponent
        float* Vh = V + (size_t)bh * VSTRIDE;
        Vh[4 * lane + 0] = o0; Vh[4 * lane + 1] = o1;
        Vh[4 * lane + 2] = o2; Vh[4 * lane + 3] = o3;
        if (lane == 63) Vh[256] = o4;
        if (lane == 0)  E[bh] = Eacc;
#undef BSTEP
#undef FSTEP
#undef RENORM
    }
#undef PROC8
#undef WAITN
#undef ISSUE8
}

// Combine: P = sum_s alphaF(s)*betaB(s) in DOUBLE (fp32 product of two
// max-normalized fields underflows when argmax states misalign).
__global__ __launch_bounds__(64) void combine(const float* __restrict__ V,
                                              const int* __restrict__ E,
                                              const float* __restrict__ accW,
                                              float* __restrict__ loss) {
    const int b = blockIdx.x, lane = threadIdx.x;
    const float* Vf = V + (size_t)(2 * b) * VSTRIDE;
    const float* Vb = Vf + VSTRIDE;
    const float4 a = *reinterpret_cast<const float4*>(Vf + 4 * lane);
    const float4 c = *reinterpret_cast<const float4*>(Vb + 4 * lane);
    double p = (double)a.x * (double)c.x + (double)a.y * (double)c.y
             + (double)a.z * (double)c.z + (double)a.w * (double)c.w;
    if (lane == 63) p += (double)Vf[256] * (double)Vb[256];
    #pragma unroll
    for (int off = 32; off > 0; off >>= 1) p += __shfl_xor(p, off, 64);
    if (lane == 0) {
        float ls = 0.0f;
        #pragma unroll
        for (int j = 0; j < 8; ++j) ls += accW[8 * b + j];
        const double lg = log(p) + (double)(E[2 * b] + E[2 * b + 1]) * LN2D - (double)ls;
        loss[b] = -(float)lg;
    }
}

// Deterministic mean over B=256 losses
__global__ __launch_bounds__(256) void finalize(const float* __restrict__ loss,
                                                float* __restrict__ out) {
    __shared__ float red[256];
    const int tid = threadIdx.x;
    red[tid] = loss[tid];
    __syncthreads();
    for (int off = 128; off > 0; off >>= 1) {
        if (tid < off) red[tid] += red[tid + off];
        __syncthreads();
    }
    if (tid == 0) out[0] = red[0] * (1.0f / 256.0f);
}

extern "C" void kernel_launch(void* const* d_in, const int* in_sizes, int n_in,
                              void* d_out, int out_size, void* d_ws, size_t ws_size,
                              hipStream_t stream) {
    constexpr int B = 256;
    const int*   y_true = (const int*)d_in[0];
    const float* y_pred = (const float*)d_in[1];
    float* out = (float*)d_out;

    float* V    = (float*)d_ws;                       // 512 * 260 floats
    int*   E    = (int*)(V + 512 * VSTRIDE);          // 512 ints
    float* accW = (float*)(E + 512);                  // 512 * 4 floats
    float* loss = accW + 2048;                        // 256 floats

    ctc_half<<<B * 2, 256, 0, stream>>>(y_true, y_pred, V, E, accW);
    combine<<<B, 64, 0, stream>>>(V, E, accW, loss);
    finalize<<<1, 256, 0, stream>>>(loss, out);
}